// Round 8
// baseline (288.161 us; speedup 1.0000x reference)
//
#include <hip/hip_runtime.h>
#include <hip/hip_bf16.h>

#define IN_DIM 256
#define HEADS 4
#define HID 64
#define NEG_SLOPE 0.2f

typedef float f32x4 __attribute__((ext_vector_type(4)));
typedef short bf16x8 __attribute__((ext_vector_type(8)));
typedef unsigned short u16x8 __attribute__((ext_vector_type(8)));

__device__ __forceinline__ unsigned short f2bf(float f) {
    unsigned u = __float_as_uint(f);
    unsigned r = u + 0x7fffu + ((u >> 16) & 1u);   // RNE
    return (unsigned short)(r >> 16);
}
__device__ __forceinline__ float bf2f(unsigned short b) {
    return __uint_as_float(((unsigned)b) << 16);
}
__device__ __forceinline__ unsigned short f2h(float f) {
    _Float16 h = (_Float16)f;
    unsigned short u; __builtin_memcpy(&u, &h, 2); return u;
}
__device__ __forceinline__ float h2f(unsigned short u) {
    _Float16 h; __builtin_memcpy(&h, &u, 2); return (float)h;
}
__device__ __forceinline__ float esel(const int4& q, int h) {
    int w = (h & 2) ? q.z : q.y;
    unsigned short u = (unsigned short)((h & 1) ? (w >> 16) : (w & 0xffff));
    return h2f(u);
}
__device__ __forceinline__ void gload16(const void* g, void* l) {
    __builtin_amdgcn_global_load_lds(
        (const __attribute__((address_space(1))) unsigned int*)g,
        (__attribute__((address_space(3))) unsigned int*)l, 16, 0, 0);
}

// ---------- D1: zero count + cast x -> bf16 + cast/transpose W ----------
__global__ __launch_bounds__(256) void prep0_kernel(
        const float* __restrict__ x, unsigned short* __restrict__ xb, int n8,
        const float* __restrict__ W, unsigned short* __restrict__ wt,
        int* __restrict__ count, int N) {
    const int gsz = gridDim.x * 256;
    const int g0 = blockIdx.x * 256 + threadIdx.x;
    for (int i = g0; i < N; i += gsz) count[i] = 0;
    for (int i = g0; i < n8; i += gsz) {
        const float4* p = (const float4*)x + (size_t)i * 2;
        float4 a = p[0], b = p[1];
        u16x8 o;
        o[0] = f2bf(a.x); o[1] = f2bf(a.y); o[2] = f2bf(a.z); o[3] = f2bf(a.w);
        o[4] = f2bf(b.x); o[5] = f2bf(b.y); o[6] = f2bf(b.z); o[7] = f2bf(b.w);
        *(u16x8*)(xb + (size_t)i * 8) = o;
    }
    for (int i = g0; i < 256 * 256; i += gsz) {
        int n = i & 255, k = i >> 8;
        wt[n * 256 + k] = f2bf(W[k * 256 + n]);
    }
}

// ---------- D2: MFMA GEMM + fused el/er  UNION  dst-histogram ----------
#define BM 64
#define BK 64
__global__ __launch_bounds__(256) void gemm_hist_kernel(
        const unsigned short* __restrict__ xb, const unsigned short* __restrict__ wt,
        const float* __restrict__ attn_l, const float* __restrict__ attn_r,
        unsigned short* __restrict__ featb, float* __restrict__ el,
        float* __restrict__ er, int N, int GB,
        const int* __restrict__ dst, int* __restrict__ count, int E) {
    if ((int)blockIdx.x >= GB) {
        const int hsz = (gridDim.x - GB) * 256;
        for (int i = ((int)blockIdx.x - GB) * 256 + threadIdx.x; i < E; i += hsz)
            atomicAdd(&count[dst[i]], 1);
        return;
    }
    __shared__ unsigned short As[BM * BK];       // 8 KB
    __shared__ unsigned short Bs[256 * BK];      // 32 KB
    const int tid = threadIdx.x;
    const int lane = tid & 63;
    const int wv = tid >> 6;
    const int bm = blockIdx.x * BM;

    f32x4 acc[4][4] = {};

    for (int k0 = 0; k0 < IN_DIM; k0 += BK) {
        #pragma unroll
        for (int r = 0; r < 2; ++r) {
            int i = r * 256 + tid;
            int row = i >> 3, slot = (i & 7) ^ (row & 7);
            int grow = bm + row; if (grow >= N) grow = N - 1;
            gload16(xb + (size_t)grow * IN_DIM + k0 + slot * 8,
                    (char*)As + (size_t)(r * 256 + (wv << 6)) * 16);
        }
        #pragma unroll
        for (int r = 0; r < 8; ++r) {
            int i = r * 256 + tid;
            int row = i >> 3, slot = (i & 7) ^ (row & 7);
            gload16(wt + (size_t)row * IN_DIM + k0 + slot * 8,
                    (char*)Bs + (size_t)(r * 256 + (wv << 6)) * 16);
        }
        __syncthreads();
        #pragma unroll
        for (int kk = 0; kk < 2; ++kk) {
            const int k16 = kk * 4 + (lane >> 4);
            bf16x8 af[4], bg[4];
            #pragma unroll
            for (int m = 0; m < 4; ++m) {
                int row = m * 16 + (lane & 15);
                af[m] = *(const bf16x8*)((const char*)As + row * 128 + ((k16 ^ (row & 7)) << 4));
            }
            #pragma unroll
            for (int n = 0; n < 4; ++n) {
                int row = (wv << 6) + n * 16 + (lane & 15);
                bg[n] = *(const bf16x8*)((const char*)Bs + row * 128 + ((k16 ^ (row & 7)) << 4));
            }
            #pragma unroll
            for (int m = 0; m < 4; ++m)
                #pragma unroll
                for (int n = 0; n < 4; ++n)
                    acc[m][n] = __builtin_amdgcn_mfma_f32_16x16x32_bf16(af[m], bg[n], acc[m][n], 0, 0, 0);
        }
        __syncthreads();
    }

    const int c15 = lane & 15;
    float al0 = attn_l[(wv << 6) + c15],      ar0 = attn_r[(wv << 6) + c15];
    float al1 = attn_l[(wv << 6) + 16 + c15], ar1 = attn_r[(wv << 6) + 16 + c15];
    float al2 = attn_l[(wv << 6) + 32 + c15], ar2 = attn_r[(wv << 6) + 32 + c15];
    float al3 = attn_l[(wv << 6) + 48 + c15], ar3 = attn_r[(wv << 6) + 48 + c15];

    #pragma unroll
    for (int m = 0; m < 4; ++m) {
        #pragma unroll
        for (int j = 0; j < 4; ++j) {
            int row = bm + m * 16 + ((lane >> 4) << 2) + j;
            bool ok = row < N;
            if (ok) {
                #pragma unroll
                for (int n = 0; n < 4; ++n)
                    featb[(size_t)row * IN_DIM + (wv << 6) + n * 16 + c15] = f2bf(acc[m][n][j]);
            }
            float pl = acc[m][0][j] * al0 + acc[m][1][j] * al1 + acc[m][2][j] * al2 + acc[m][3][j] * al3;
            float pr = acc[m][0][j] * ar0 + acc[m][1][j] * ar1 + acc[m][2][j] * ar2 + acc[m][3][j] * ar3;
            #pragma unroll
            for (int off = 1; off < 16; off <<= 1) {
                pl += __shfl_xor(pl, off);
                pr += __shfl_xor(pr, off);
            }
            if (ok && c15 == 0) {
                el[row * HEADS + wv] = pl;
                er[row * HEADS + wv] = pr;
            }
        }
    }
}

// ---------- D3: single-dispatch scan (each block recomputes its prefix) ----
__global__ __launch_bounds__(256) void scan_kernel(
        const int* __restrict__ count, int* __restrict__ row_start,
        int* __restrict__ cursor, int N) {
    __shared__ int ws[4];
    __shared__ int boff_s;
    const int c = blockIdx.x;
    const int tid = threadIdx.x, lane = tid & 63, wv = tid >> 6;
    int lim = c * 256; if (lim > N) lim = N;
    int acc = 0;
    for (int j = tid; j < lim; j += 256) acc += count[j];
    #pragma unroll
    for (int off = 1; off < 64; off <<= 1) acc += __shfl_xor(acc, off);
    if (lane == 0) ws[wv] = acc;
    __syncthreads();
    if (tid == 0) boff_s = ws[0] + ws[1] + ws[2] + ws[3];
    __syncthreads();
    int i = c * 256 + tid;
    int v = (i < N) ? count[i] : 0;
    int incl = v;
    #pragma unroll
    for (int off = 1; off < 64; off <<= 1) {
        int t = __shfl_up(incl, off);
        if (lane >= off) incl += t;
    }
    if (lane == 63) ws[wv] = incl;
    __syncthreads();
    int wofs = 0;
    #pragma unroll
    for (int w = 0; w < 4; ++w) if (w < wv) wofs += ws[w];
    int excl = boff_s + wofs + incl - v;
    if (i < N) { row_start[i] = excl; cursor[i] = excl; }
    else if (i == N) row_start[N] = excl;
}

// ---------- D4: scatter + edge-score precompute ----------
__global__ __launch_bounds__(256) void scatter_score_kernel(
        const int* __restrict__ src, const int* __restrict__ dst,
        const float* __restrict__ el, const float* __restrict__ er,
        int* __restrict__ cursor, int4* __restrict__ pay, int E) {
    int i = blockIdx.x * 256 + threadIdx.x;
    if (i >= E) return;
    int s = src[i], d = dst[i];
    float4 l = ((const float4*)el)[s];
    float4 r = ((const float4*)er)[d];
    float v0 = l.x + r.x, v1 = l.y + r.y, v2 = l.z + r.z, v3 = l.w + r.w;
    v0 = v0 > 0.f ? v0 : NEG_SLOPE * v0;
    v1 = v1 > 0.f ? v1 : NEG_SLOPE * v1;
    v2 = v2 > 0.f ? v2 : NEG_SLOPE * v2;
    v3 = v3 > 0.f ? v3 : NEG_SLOPE * v3;
    int e01 = (int)f2h(__expf(v0)) | ((int)f2h(__expf(v1)) << 16);
    int e23 = (int)f2h(__expf(v2)) | ((int)f2h(__expf(v3)) << 16);
    int pos = atomicAdd(&cursor[d], 1);
    pay[pos] = make_int4(s, e01, e23, 0);
}

// ---------- D5: fused normalize + aggregate, 3-stage software pipeline ----
// Per 4-edge group: pay loads (wave-uniform -> SMEM/lgkmcnt path) prefetched
// 2 groups ahead; feat gathers (vmcnt) prefetched 1 group ahead; FMAs consume
// the group issued last iteration. 2-phase unrolled (A/B banks) -> zero-move
// rotation; banks hold only {src, e} (esel extracted at load time).
#define FEAT4(s) (*(const ushort4*)(featb + ((size_t)(s) << 8) + col))
#define FMA1(E,F) do { dh += (E); ax += (E) * bf2f((F).x); ay += (E) * bf2f((F).y); \
                       az += (E) * bf2f((F).z); aw += (E) * bf2f((F).w); } while (0)
#define AGG_ONE(Q) do {                                             \
    float e_ = esel((Q), h);                                        \
    dh += e_;                                                       \
    ushort4 fv_ = *(const ushort4*)(featb + ((size_t)(Q).x << 8) + col); \
    ax += e_ * bf2f(fv_.x); ay += e_ * bf2f(fv_.y);                 \
    az += e_ * bf2f(fv_.z); aw += e_ * bf2f(fv_.w); } while (0)

__global__ __launch_bounds__(256) void node_aggregate_kernel(
        const unsigned short* __restrict__ featb, const int4* __restrict__ pay,
        const int* __restrict__ row_start, float* __restrict__ out, int N) {
    int wid = blockIdx.x * 4 + (threadIdx.x >> 6);
    int lane = threadIdx.x & 63;
    if (wid >= N) return;
    const int beg = row_start[wid], end = row_start[wid + 1];
    if (beg == end) {
        if (lane < 16) *(float4*)(out + (size_t)wid * HID + lane * 4) = make_float4(0.f, 0.f, 0.f, 0.f);
        return;
    }
    const int h = lane >> 4;
    const int col = lane * 4;

    float dh = 0.f, ax = 0.f, ay = 0.f, az = 0.f, aw = 0.f;
    const int ngrp = (end - beg) >> 2;
    int p = beg;

    if (ngrp >= 2) {
        int sA0, sA1, sA2, sA3, sB0, sB1, sB2, sB3;
        float eA0, eA1, eA2, eA3, eB0, eB1, eB2, eB3;
        {
            int4 t0 = pay[p], t1 = pay[p + 1], t2 = pay[p + 2], t3 = pay[p + 3];
            int4 u0 = pay[p + 4], u1 = pay[p + 5], u2 = pay[p + 6], u3 = pay[p + 7];
            sA0 = t0.x; eA0 = esel(t0, h); sA1 = t1.x; eA1 = esel(t1, h);
            sA2 = t2.x; eA2 = esel(t2, h); sA3 = t3.x; eA3 = esel(t3, h);
            sB0 = u0.x; eB0 = esel(u0, h); sB1 = u1.x; eB1 = esel(u1, h);
            sB2 = u2.x; eB2 = esel(u2, h); sB3 = u3.x; eB3 = esel(u3, h);
        }
        p += 8;
        ushort4 fA0 = FEAT4(sA0), fA1 = FEAT4(sA1), fA2 = FEAT4(sA2), fA3 = FEAT4(sA3);
        int g = 0;
        for (; g + 3 < ngrp; g += 2) {
            // phase 1: consume A (grp g); B = grp g+1; refill A with grp g+2
            ushort4 fB0 = FEAT4(sB0), fB1 = FEAT4(sB1), fB2 = FEAT4(sB2), fB3 = FEAT4(sB3);
            int4 t0 = pay[p], t1 = pay[p + 1], t2 = pay[p + 2], t3 = pay[p + 3]; p += 4;
            FMA1(eA0, fA0); FMA1(eA1, fA1); FMA1(eA2, fA2); FMA1(eA3, fA3);
            sA0 = t0.x; eA0 = esel(t0, h); sA1 = t1.x; eA1 = esel(t1, h);
            sA2 = t2.x; eA2 = esel(t2, h); sA3 = t3.x; eA3 = esel(t3, h);
            // phase 2: consume B (grp g+1); A = grp g+2; refill B with grp g+3
            fA0 = FEAT4(sA0); fA1 = FEAT4(sA1); fA2 = FEAT4(sA2); fA3 = FEAT4(sA3);
            int4 u0 = pay[p], u1 = pay[p + 1], u2 = pay[p + 2], u3 = pay[p + 3]; p += 4;
            FMA1(eB0, fB0); FMA1(eB1, fB1); FMA1(eB2, fB2); FMA1(eB3, fB3);
            sB0 = u0.x; eB0 = esel(u0, h); sB1 = u1.x; eB1 = esel(u1, h);
            sB2 = u2.x; eB2 = esel(u2, h); sB3 = u3.x; eB3 = esel(u3, h);
        }
        if (ngrp - g == 3) {          // one unloaded group remains
            ushort4 fB0 = FEAT4(sB0), fB1 = FEAT4(sB1), fB2 = FEAT4(sB2), fB3 = FEAT4(sB3);
            int4 t0 = pay[p], t1 = pay[p + 1], t2 = pay[p + 2], t3 = pay[p + 3]; p += 4;
            FMA1(eA0, fA0); FMA1(eA1, fA1); FMA1(eA2, fA2); FMA1(eA3, fA3);
            sA0 = t0.x; eA0 = esel(t0, h); sA1 = t1.x; eA1 = esel(t1, h);
            sA2 = t2.x; eA2 = esel(t2, h); sA3 = t3.x; eA3 = esel(t3, h);
            fA0 = FEAT4(sA0); fA1 = FEAT4(sA1); fA2 = FEAT4(sA2); fA3 = FEAT4(sA3);
            FMA1(eB0, fB0); FMA1(eB1, fB1); FMA1(eB2, fB2); FMA1(eB3, fB3);
            FMA1(eA0, fA0); FMA1(eA1, fA1); FMA1(eA2, fA2); FMA1(eA3, fA3);
        } else {                      // exactly A and B remain
            ushort4 fB0 = FEAT4(sB0), fB1 = FEAT4(sB1), fB2 = FEAT4(sB2), fB3 = FEAT4(sB3);
            FMA1(eA0, fA0); FMA1(eA1, fA1); FMA1(eA2, fA2); FMA1(eA3, fA3);
            FMA1(eB0, fB0); FMA1(eB1, fB1); FMA1(eB2, fB2); FMA1(eB3, fB3);
        }
    } else if (ngrp == 1) {
        int4 q0 = pay[p], q1 = pay[p + 1], q2 = pay[p + 2], q3 = pay[p + 3];
        p += 4;
        AGG_ONE(q0); AGG_ONE(q1); AGG_ONE(q2); AGG_ONE(q3);
    }
    for (; p < end; ++p) { int4 q = pay[p]; AGG_ONE(q); }

    float inv = 1.f / dh;
    float rx = ax * inv, ry = ay * inv, rz = az * inv, rw = aw * inv;
    rx += __shfl_xor(rx, 16); ry += __shfl_xor(ry, 16);
    rz += __shfl_xor(rz, 16); rw += __shfl_xor(rw, 16);
    rx += __shfl_xor(rx, 32); ry += __shfl_xor(ry, 32);
    rz += __shfl_xor(rz, 32); rw += __shfl_xor(rw, 32);
    if (lane < 16) {
        *(float4*)(out + (size_t)wid * HID + lane * 4) =
            make_float4(0.25f * rx, 0.25f * ry, 0.25f * rz, 0.25f * rw);
    }
}

extern "C" void kernel_launch(void* const* d_in, const int* in_sizes, int n_in,
                              void* d_out, int out_size, void* d_ws, size_t ws_size,
                              hipStream_t stream) {
    const float* x      = (const float*)d_in[0];
    const float* W      = (const float*)d_in[1];
    const float* attn_l = (const float*)d_in[2];
    const float* attn_r = (const float*)d_in[3];
    const int*   src    = (const int*)d_in[4];
    const int*   dst    = (const int*)d_in[5];
    float* out = (float*)d_out;

    const int N = in_sizes[0] / IN_DIM;   // 50000
    const int E = in_sizes[4];            // 800000

    // workspace layout (16B-aligned sections). pay ALIASES xb (disjoint
    // lifetimes: xb dead after D2; pay written in D4, read in D5).
    unsigned short* xb    = (unsigned short*)d_ws;              // N*256 bf16
    unsigned short* wtp   = xb + (size_t)N * IN_DIM;            // 256*256 bf16
    unsigned short* featb = wtp + 256 * 256;                    // N*256 bf16
    float* el        = (float*)(featb + (size_t)N * IN_DIM);    // N*4
    float* er        = el + (size_t)N * HEADS;                  // N*4
    int*   count     = (int*)(er + (size_t)N * HEADS);          // N
    int*   row_start = count + N;                               // N+1 (+pad)
    int*   cursor    = row_start + N + 4;                       // N
    int4*  pay       = (int4*)xb;                               // E x 16B (alias)

    const int NB = (N + 1 + 255) / 256;
    const int n8 = N * IN_DIM / 8;
    const int GB = (N + BM - 1) / BM;
    const int HB = 256;

    // D1: zero count + cast x + cast/transpose W
    prep0_kernel<<<2048, 256, 0, stream>>>(x, xb, n8, W, wtp, count, N);

    // D2: GEMM(+el/er) ∪ dst histogram
    gemm_hist_kernel<<<GB + HB, 256, 0, stream>>>(
        xb, wtp, attn_l, attn_r, featb, el, er, N, GB, dst, count, E);

    // D3: scan -> row_start, cursor
    scan_kernel<<<NB, 256, 0, stream>>>(count, row_start, cursor, N);

    // D4: scatter + edge-score precompute
    scatter_score_kernel<<<(E + 255) / 256, 256, 0, stream>>>(
        src, dst, el, er, cursor, pay, E);

    // D5: fused normalize + aggregate (software-pipelined)
    node_aggregate_kernel<<<(N * 64 + 255) / 256, 256, 0, stream>>>(
        featb, pay, row_start, out, N);
}

// Round 9
// 269.546 us; speedup vs baseline: 1.0691x; 1.0691x over previous
//
#include <hip/hip_runtime.h>
#include <hip/hip_bf16.h>

#define IN_DIM 256
#define HEADS 4
#define HID 64
#define NEG_SLOPE 0.2f

typedef float f32x4 __attribute__((ext_vector_type(4)));
typedef short bf16x8 __attribute__((ext_vector_type(8)));
typedef unsigned short u16x8 __attribute__((ext_vector_type(8)));

__device__ __forceinline__ unsigned short f2bf(float f) {
    unsigned u = __float_as_uint(f);
    unsigned r = u + 0x7fffu + ((u >> 16) & 1u);   // RNE
    return (unsigned short)(r >> 16);
}
__device__ __forceinline__ float bf2f(unsigned short b) {
    return __uint_as_float(((unsigned)b) << 16);
}
__device__ __forceinline__ unsigned short f2h(float f) {
    _Float16 h = (_Float16)f;
    unsigned short u; __builtin_memcpy(&u, &h, 2); return u;
}
__device__ __forceinline__ float h2f(unsigned short u) {
    _Float16 h; __builtin_memcpy(&h, &u, 2); return (float)h;
}
__device__ __forceinline__ float esel(const int4& q, int h) {
    int w = (h & 2) ? q.z : q.y;
    unsigned short u = (unsigned short)((h & 1) ? (w >> 16) : (w & 0xffff));
    return h2f(u);
}
__device__ __forceinline__ void gload16(const void* g, void* l) {
    __builtin_amdgcn_global_load_lds(
        (const __attribute__((address_space(1))) unsigned int*)g,
        (__attribute__((address_space(3))) unsigned int*)l, 16, 0, 0);
}

// ---------- D1: zero count + cast/transpose W (tiny) ----------
__global__ __launch_bounds__(256) void prep0_kernel(
        const float* __restrict__ W, unsigned short* __restrict__ wt,
        int* __restrict__ count, int N) {
    const int gsz = gridDim.x * 256;
    const int g0 = blockIdx.x * 256 + threadIdx.x;
    for (int i = g0; i < N; i += gsz) count[i] = 0;
    for (int i = g0; i < 256 * 256; i += gsz) {
        int n = i & 255, k = i >> 8;
        wt[n * 256 + k] = f2bf(W[k * 256 + n]);
    }
}

// ---------- D2: MFMA GEMM (f32 A, inline cast) + fused el/er  U  hist ------
// blocks [0,GB): GEMM, BM=64 rows x full 256 cols; A staged from f32 x via
// regs (cast+ds_write, pre-swizzled slots); B via async gload16 from bf16 wt.
// wave wv owns cols [64wv,64wv+64) == head wv -> el/er in epilogue.
// blocks [GB,..): grid-stride dst histogram.
#define BM 64
#define BK 64
__global__ __launch_bounds__(256) void gemm_hist_kernel(
        const float* __restrict__ x, const unsigned short* __restrict__ wt,
        const float* __restrict__ attn_l, const float* __restrict__ attn_r,
        unsigned short* __restrict__ featb, float* __restrict__ el,
        float* __restrict__ er, int N, int GB,
        const int* __restrict__ dst, int* __restrict__ count, int E) {
    if ((int)blockIdx.x >= GB) {
        const int hsz = (gridDim.x - GB) * 256;
        for (int i = ((int)blockIdx.x - GB) * 256 + threadIdx.x; i < E; i += hsz)
            atomicAdd(&count[dst[i]], 1);
        return;
    }
    __shared__ unsigned short As[BM * BK];       // 8 KB
    __shared__ unsigned short Bs[256 * BK];      // 32 KB
    const int tid = threadIdx.x;
    const int lane = tid & 63;
    const int wv = tid >> 6;
    const int bm = blockIdx.x * BM;

    f32x4 acc[4][4] = {};

    for (int k0 = 0; k0 < IN_DIM; k0 += BK) {
        // A: 512 slots x 16B; slot s of row holds global k-chunk (s^(row&7)).
        // Read f32 x, cast in regs, ds_write_b128 to linear slot.
        #pragma unroll
        for (int r = 0; r < 2; ++r) {
            int i = r * 256 + tid;
            int row = i >> 3, s = i & 7;
            int grow = bm + row; if (grow >= N) grow = N - 1;
            int gc = s ^ (row & 7);
            const float4* xp = (const float4*)(x + (size_t)grow * IN_DIM + k0 + gc * 8);
            float4 a0 = xp[0], a1 = xp[1];
            u16x8 o;
            o[0] = f2bf(a0.x); o[1] = f2bf(a0.y); o[2] = f2bf(a0.z); o[3] = f2bf(a0.w);
            o[4] = f2bf(a1.x); o[5] = f2bf(a1.y); o[6] = f2bf(a1.z); o[7] = f2bf(a1.w);
            *(u16x8*)((char*)As + (size_t)i * 16) = o;
        }
        // B: 2048 slots x 16B via async global->LDS (wave-linear dest)
        #pragma unroll
        for (int r = 0; r < 8; ++r) {
            int i = r * 256 + tid;
            int row = i >> 3, slot = (i & 7) ^ (row & 7);
            gload16(wt + (size_t)row * IN_DIM + k0 + slot * 8,
                    (char*)Bs + (size_t)(r * 256 + (wv << 6)) * 16);
        }
        __syncthreads();
        #pragma unroll
        for (int kk = 0; kk < 2; ++kk) {
            const int k16 = kk * 4 + (lane >> 4);
            bf16x8 af[4], bg[4];
            #pragma unroll
            for (int m = 0; m < 4; ++m) {
                int row = m * 16 + (lane & 15);
                af[m] = *(const bf16x8*)((const char*)As + row * 128 + ((k16 ^ (row & 7)) << 4));
            }
            #pragma unroll
            for (int n = 0; n < 4; ++n) {
                int row = (wv << 6) + n * 16 + (lane & 15);
                bg[n] = *(const bf16x8*)((const char*)Bs + row * 128 + ((k16 ^ (row & 7)) << 4));
            }
            #pragma unroll
            for (int m = 0; m < 4; ++m)
                #pragma unroll
                for (int n = 0; n < 4; ++n)
                    acc[m][n] = __builtin_amdgcn_mfma_f32_16x16x32_bf16(af[m], bg[n], acc[m][n], 0, 0, 0);
        }
        __syncthreads();
    }

    const int c15 = lane & 15;
    float al0 = attn_l[(wv << 6) + c15],      ar0 = attn_r[(wv << 6) + c15];
    float al1 = attn_l[(wv << 6) + 16 + c15], ar1 = attn_r[(wv << 6) + 16 + c15];
    float al2 = attn_l[(wv << 6) + 32 + c15], ar2 = attn_r[(wv << 6) + 32 + c15];
    float al3 = attn_l[(wv << 6) + 48 + c15], ar3 = attn_r[(wv << 6) + 48 + c15];

    #pragma unroll
    for (int m = 0; m < 4; ++m) {
        #pragma unroll
        for (int j = 0; j < 4; ++j) {
            int row = bm + m * 16 + ((lane >> 4) << 2) + j;
            bool ok = row < N;
            if (ok) {
                #pragma unroll
                for (int n = 0; n < 4; ++n)
                    featb[(size_t)row * IN_DIM + (wv << 6) + n * 16 + c15] = f2bf(acc[m][n][j]);
            }
            float pl = acc[m][0][j] * al0 + acc[m][1][j] * al1 + acc[m][2][j] * al2 + acc[m][3][j] * al3;
            float pr = acc[m][0][j] * ar0 + acc[m][1][j] * ar1 + acc[m][2][j] * ar2 + acc[m][3][j] * ar3;
            #pragma unroll
            for (int off = 1; off < 16; off <<= 1) {
                pl += __shfl_xor(pl, off);
                pr += __shfl_xor(pr, off);
            }
            if (ok && c15 == 0) {
                el[row * HEADS + wv] = pl;
                er[row * HEADS + wv] = pr;
            }
        }
    }
}

// ---------- D3: single-dispatch scan (each block recomputes its prefix) ----
__global__ __launch_bounds__(256) void scan_kernel(
        const int* __restrict__ count, int* __restrict__ row_start,
        int* __restrict__ cursor, int N) {
    __shared__ int ws[4];
    __shared__ int boff_s;
    const int c = blockIdx.x;
    const int tid = threadIdx.x, lane = tid & 63, wv = tid >> 6;
    int lim = c * 256; if (lim > N) lim = N;
    int acc = 0;
    for (int j = tid; j < lim; j += 256) acc += count[j];
    #pragma unroll
    for (int off = 1; off < 64; off <<= 1) acc += __shfl_xor(acc, off);
    if (lane == 0) ws[wv] = acc;
    __syncthreads();
    if (tid == 0) boff_s = ws[0] + ws[1] + ws[2] + ws[3];
    __syncthreads();
    int i = c * 256 + tid;
    int v = (i < N) ? count[i] : 0;
    int incl = v;
    #pragma unroll
    for (int off = 1; off < 64; off <<= 1) {
        int t = __shfl_up(incl, off);
        if (lane >= off) incl += t;
    }
    if (lane == 63) ws[wv] = incl;
    __syncthreads();
    int wofs = 0;
    #pragma unroll
    for (int w = 0; w < 4; ++w) if (w < wv) wofs += ws[w];
    int excl = boff_s + wofs + incl - v;
    if (i < N) { row_start[i] = excl; cursor[i] = excl; }
    else if (i == N) row_start[N] = excl;
}

// ---------- D4: scatter + edge-score precompute ----------
__global__ __launch_bounds__(256) void scatter_score_kernel(
        const int* __restrict__ src, const int* __restrict__ dst,
        const float* __restrict__ el, const float* __restrict__ er,
        int* __restrict__ cursor, int4* __restrict__ pay, int E) {
    int i = blockIdx.x * 256 + threadIdx.x;
    if (i >= E) return;
    int s = src[i], d = dst[i];
    float4 l = ((const float4*)el)[s];
    float4 r = ((const float4*)er)[d];
    float v0 = l.x + r.x, v1 = l.y + r.y, v2 = l.z + r.z, v3 = l.w + r.w;
    v0 = v0 > 0.f ? v0 : NEG_SLOPE * v0;
    v1 = v1 > 0.f ? v1 : NEG_SLOPE * v1;
    v2 = v2 > 0.f ? v2 : NEG_SLOPE * v2;
    v3 = v3 > 0.f ? v3 : NEG_SLOPE * v3;
    int e01 = (int)f2h(__expf(v0)) | ((int)f2h(__expf(v1)) << 16);
    int e23 = (int)f2h(__expf(v2)) | ((int)f2h(__expf(v3)) << 16);
    int pos = atomicAdd(&cursor[d], 1);
    pay[pos] = make_int4(s, e01, e23, 0);
}

// ---------- D5: fused normalize + aggregate (R7-proven: 4-way, 28 VGPR) ----
#define AGG_ONE(Q) do {                                             \
    float e_ = esel((Q), h);                                        \
    dh += e_;                                                       \
    ushort4 fv_ = *(const ushort4*)(featb + ((size_t)(Q).x << 8) + col); \
    ax += e_ * bf2f(fv_.x); ay += e_ * bf2f(fv_.y);                 \
    az += e_ * bf2f(fv_.z); aw += e_ * bf2f(fv_.w); } while (0)

__global__ __launch_bounds__(256) void node_aggregate_kernel(
        const unsigned short* __restrict__ featb, const int4* __restrict__ pay,
        const int* __restrict__ row_start, float* __restrict__ out, int N) {
    int wid = blockIdx.x * 4 + (threadIdx.x >> 6);
    int lane = threadIdx.x & 63;
    if (wid >= N) return;
    const int beg = row_start[wid], end = row_start[wid + 1];
    if (beg == end) {
        if (lane < 16) *(float4*)(out + (size_t)wid * HID + lane * 4) = make_float4(0.f, 0.f, 0.f, 0.f);
        return;
    }
    const int h = lane >> 4;
    const int col = lane * 4;

    float dh = 0.f, ax = 0.f, ay = 0.f, az = 0.f, aw = 0.f;
    int p = beg;
    for (; p + 4 <= end; p += 4) {
        int4 q0 = pay[p], q1 = pay[p + 1], q2 = pay[p + 2], q3 = pay[p + 3];
        float e0 = esel(q0, h), e1 = esel(q1, h), e2 = esel(q2, h), e3 = esel(q3, h);
        ushort4 f0 = *(const ushort4*)(featb + ((size_t)q0.x << 8) + col);
        ushort4 f1 = *(const ushort4*)(featb + ((size_t)q1.x << 8) + col);
        ushort4 f2 = *(const ushort4*)(featb + ((size_t)q2.x << 8) + col);
        ushort4 f3 = *(const ushort4*)(featb + ((size_t)q3.x << 8) + col);
        dh += (e0 + e1) + (e2 + e3);
        ax += e0 * bf2f(f0.x) + e1 * bf2f(f1.x) + e2 * bf2f(f2.x) + e3 * bf2f(f3.x);
        ay += e0 * bf2f(f0.y) + e1 * bf2f(f1.y) + e2 * bf2f(f2.y) + e3 * bf2f(f3.y);
        az += e0 * bf2f(f0.z) + e1 * bf2f(f1.z) + e2 * bf2f(f2.z) + e3 * bf2f(f3.z);
        aw += e0 * bf2f(f0.w) + e1 * bf2f(f1.w) + e2 * bf2f(f2.w) + e3 * bf2f(f3.w);
    }
    for (; p < end; ++p) { int4 q = pay[p]; AGG_ONE(q); }

    float inv = 1.f / dh;
    float rx = ax * inv, ry = ay * inv, rz = az * inv, rw = aw * inv;
    rx += __shfl_xor(rx, 16); ry += __shfl_xor(ry, 16);
    rz += __shfl_xor(rz, 16); rw += __shfl_xor(rw, 16);
    rx += __shfl_xor(rx, 32); ry += __shfl_xor(ry, 32);
    rz += __shfl_xor(rz, 32); rw += __shfl_xor(rw, 32);
    if (lane < 16) {
        *(float4*)(out + (size_t)wid * HID + lane * 4) =
            make_float4(0.25f * rx, 0.25f * ry, 0.25f * rz, 0.25f * rw);
    }
}

extern "C" void kernel_launch(void* const* d_in, const int* in_sizes, int n_in,
                              void* d_out, int out_size, void* d_ws, size_t ws_size,
                              hipStream_t stream) {
    const float* x      = (const float*)d_in[0];
    const float* W      = (const float*)d_in[1];
    const float* attn_l = (const float*)d_in[2];
    const float* attn_r = (const float*)d_in[3];
    const int*   src    = (const int*)d_in[4];
    const int*   dst    = (const int*)d_in[5];
    float* out = (float*)d_out;

    const int N = in_sizes[0] / IN_DIM;   // 50000
    const int E = in_sizes[4];            // 800000

    // workspace layout (16B-aligned sections). pay occupies the first region
    // (formerly xb; x is now read f32 directly by the GEMM).
    int4*  pay       = (int4*)d_ws;                             // E x 16B
    unsigned short* wtp   = (unsigned short*)d_ws + (size_t)N * IN_DIM; // 256*256 bf16
    unsigned short* featb = wtp + 256 * 256;                    // N*256 bf16
    float* el        = (float*)(featb + (size_t)N * IN_DIM);    // N*4
    float* er        = el + (size_t)N * HEADS;                  // N*4
    int*   count     = (int*)(er + (size_t)N * HEADS);          // N
    int*   row_start = count + N;                               // N+1 (+pad)
    int*   cursor    = row_start + N + 4;                       // N

    const int NB = (N + 1 + 255) / 256;
    const int GB = (N + BM - 1) / BM;
    const int HB = 256;

    // D1: zero count + cast/transpose W
    prep0_kernel<<<256, 256, 0, stream>>>(W, wtp, count, N);

    // D2: GEMM(+el/er) ∪ dst histogram
    gemm_hist_kernel<<<GB + HB, 256, 0, stream>>>(
        x, wtp, attn_l, attn_r, featb, el, er, N, GB, dst, count, E);

    // D3: scan -> row_start, cursor
    scan_kernel<<<NB, 256, 0, stream>>>(count, row_start, cursor, N);

    // D4: scatter + edge-score precompute
    scatter_score_kernel<<<(E + 255) / 256, 256, 0, stream>>>(
        src, dst, el, er, cursor, pay, E);

    // D5: fused normalize + aggregate
    node_aggregate_kernel<<<(N * 64 + 255) / 256, 256, 0, stream>>>(
        featb, pay, row_start, out, N);
}

// Round 10
// 253.056 us; speedup vs baseline: 1.1387x; 1.0652x over previous
//
#include <hip/hip_runtime.h>
#include <hip/hip_bf16.h>

#define IN_DIM 256
#define HEADS 4
#define HID 64
#define NEG_SLOPE 0.2f

typedef float f32x4 __attribute__((ext_vector_type(4)));
typedef short bf16x8 __attribute__((ext_vector_type(8)));
typedef unsigned short u16x8 __attribute__((ext_vector_type(8)));

__device__ __forceinline__ unsigned short f2bf(float f) {
    unsigned u = __float_as_uint(f);
    unsigned r = u + 0x7fffu + ((u >> 16) & 1u);   // RNE
    return (unsigned short)(r >> 16);
}
__device__ __forceinline__ float bf2f(unsigned short b) {
    return __uint_as_float(((unsigned)b) << 16);
}
__device__ __forceinline__ unsigned short f2h(float f) {
    _Float16 h = (_Float16)f;
    unsigned short u; __builtin_memcpy(&u, &h, 2); return u;
}
__device__ __forceinline__ float h2f(unsigned short u) {
    _Float16 h; __builtin_memcpy(&h, &u, 2); return (float)h;
}
__device__ __forceinline__ float esel(const int4& q, int h) {
    int w = (h & 2) ? q.z : q.y;
    unsigned short u = (unsigned short)((h & 1) ? (w >> 16) : (w & 0xffff));
    return h2f(u);
}
__device__ __forceinline__ void gload16(const void* g, void* l) {
    __builtin_amdgcn_global_load_lds(
        (const __attribute__((address_space(1))) unsigned int*)g,
        (__attribute__((address_space(3))) unsigned int*)l, 16, 0, 0);
}

// ---------- D1: zero count + cast/transpose W (tiny) ----------
__global__ __launch_bounds__(256) void prep0_kernel(
        const float* __restrict__ W, unsigned short* __restrict__ wt,
        int* __restrict__ count, int N) {
    const int gsz = gridDim.x * 256;
    const int g0 = blockIdx.x * 256 + threadIdx.x;
    for (int i = g0; i < N; i += gsz) count[i] = 0;
    for (int i = g0; i < 256 * 256; i += gsz) {
        int n = i & 255, k = i >> 8;
        wt[n * 256 + k] = f2bf(W[k * 256 + n]);
    }
}

// ---------- D2: MFMA GEMM (f32 A inline-cast) + fused el/er  U  hist -------
// BM=128 x BN=256, 512 threads = 8 waves in a 2x4 grid: wave (wr=wv>>2,
// wc=wv&3) owns rows [64wr,64wr+64) x cols [64wc,64wc+64); wc == head, so
// el/er reduce stays wave-local in the epilogue. 48 KB LDS -> 3 blocks/CU.
// blocks [GB,..): grid-stride dst histogram.
#define BM 128
#define BK 64
__global__ __launch_bounds__(512) void gemm_hist_kernel(
        const float* __restrict__ x, const unsigned short* __restrict__ wt,
        const float* __restrict__ attn_l, const float* __restrict__ attn_r,
        unsigned short* __restrict__ featb, float* __restrict__ el,
        float* __restrict__ er, int N, int GB,
        const int* __restrict__ dst, int* __restrict__ count, int E) {
    if ((int)blockIdx.x >= GB) {
        const int hsz = (gridDim.x - GB) * 512;
        for (int i = ((int)blockIdx.x - GB) * 512 + threadIdx.x; i < E; i += hsz)
            atomicAdd(&count[dst[i]], 1);
        return;
    }
    __shared__ unsigned short As[BM * BK];       // 16 KB
    __shared__ unsigned short Bs[256 * BK];      // 32 KB
    const int tid = threadIdx.x;
    const int lane = tid & 63;
    const int wv = tid >> 6;                     // 0..7
    const int wr = wv >> 2;                      // row half
    const int wc = wv & 3;                       // col block == head
    const int bm = blockIdx.x * BM;

    f32x4 acc[4][4] = {};

    for (int k0 = 0; k0 < IN_DIM; k0 += BK) {
        // A: 1024 slots x 16B; slot s of row holds global k-chunk (s^(row&7)).
        // Read f32 x, cast in regs, ds_write_b128 to linear slot.
        #pragma unroll
        for (int r = 0; r < 2; ++r) {
            int i = r * 512 + tid;
            int row = i >> 3, s = i & 7;
            int grow = bm + row; if (grow >= N) grow = N - 1;
            int gc = s ^ (row & 7);
            const float4* xp = (const float4*)(x + (size_t)grow * IN_DIM + k0 + gc * 8);
            float4 a0 = xp[0], a1 = xp[1];
            u16x8 o;
            o[0] = f2bf(a0.x); o[1] = f2bf(a0.y); o[2] = f2bf(a0.z); o[3] = f2bf(a0.w);
            o[4] = f2bf(a1.x); o[5] = f2bf(a1.y); o[6] = f2bf(a1.z); o[7] = f2bf(a1.w);
            *(u16x8*)((char*)As + (size_t)i * 16) = o;
        }
        // B: 2048 slots x 16B via async global->LDS (wave-linear dest)
        #pragma unroll
        for (int r = 0; r < 4; ++r) {
            int i = r * 512 + tid;
            int row = i >> 3, slot = (i & 7) ^ (row & 7);
            gload16(wt + (size_t)row * IN_DIM + k0 + slot * 8,
                    (char*)Bs + (size_t)(r * 512 + (wv << 6)) * 16);
        }
        __syncthreads();
        #pragma unroll
        for (int kk = 0; kk < 2; ++kk) {
            const int k16 = kk * 4 + (lane >> 4);
            bf16x8 af[4], bg[4];
            #pragma unroll
            for (int m = 0; m < 4; ++m) {
                int row = (wr << 6) + m * 16 + (lane & 15);
                af[m] = *(const bf16x8*)((const char*)As + row * 128 + ((k16 ^ (row & 7)) << 4));
            }
            #pragma unroll
            for (int n = 0; n < 4; ++n) {
                int row = (wc << 6) + n * 16 + (lane & 15);
                bg[n] = *(const bf16x8*)((const char*)Bs + row * 128 + ((k16 ^ (row & 7)) << 4));
            }
            #pragma unroll
            for (int m = 0; m < 4; ++m)
                #pragma unroll
                for (int n = 0; n < 4; ++n)
                    acc[m][n] = __builtin_amdgcn_mfma_f32_16x16x32_bf16(af[m], bg[n], acc[m][n], 0, 0, 0);
        }
        __syncthreads();
    }

    const int c15 = lane & 15;
    float al0 = attn_l[(wc << 6) + c15],      ar0 = attn_r[(wc << 6) + c15];
    float al1 = attn_l[(wc << 6) + 16 + c15], ar1 = attn_r[(wc << 6) + 16 + c15];
    float al2 = attn_l[(wc << 6) + 32 + c15], ar2 = attn_r[(wc << 6) + 32 + c15];
    float al3 = attn_l[(wc << 6) + 48 + c15], ar3 = attn_r[(wc << 6) + 48 + c15];

    #pragma unroll
    for (int m = 0; m < 4; ++m) {
        #pragma unroll
        for (int j = 0; j < 4; ++j) {
            int row = bm + (wr << 6) + m * 16 + ((lane >> 4) << 2) + j;
            bool ok = row < N;
            // featb write (C/D layout: col=lane&15, row=(lane>>4)*4+reg)
            if (ok) {
                #pragma unroll
                for (int n = 0; n < 4; ++n)
                    featb[(size_t)row * IN_DIM + (wc << 6) + n * 16 + c15] = f2bf(acc[m][n][j]);
            }
            // el/er: dot over this row's 64 cols of head wc (16 lanes x 4 n)
            float pl = acc[m][0][j] * al0 + acc[m][1][j] * al1 + acc[m][2][j] * al2 + acc[m][3][j] * al3;
            float pr = acc[m][0][j] * ar0 + acc[m][1][j] * ar1 + acc[m][2][j] * ar2 + acc[m][3][j] * ar3;
            #pragma unroll
            for (int off = 1; off < 16; off <<= 1) {
                pl += __shfl_xor(pl, off);
                pr += __shfl_xor(pr, off);
            }
            if (ok && c15 == 0) {
                el[row * HEADS + wc] = pl;
                er[row * HEADS + wc] = pr;
            }
        }
    }
}

// ---------- D3: single-dispatch scan (each block recomputes its prefix) ----
__global__ __launch_bounds__(256) void scan_kernel(
        const int* __restrict__ count, int* __restrict__ row_start,
        int* __restrict__ cursor, int N) {
    __shared__ int ws[4];
    __shared__ int boff_s;
    const int c = blockIdx.x;
    const int tid = threadIdx.x, lane = tid & 63, wv = tid >> 6;
    int lim = c * 256; if (lim > N) lim = N;
    int acc = 0;
    for (int j = tid; j < lim; j += 256) acc += count[j];
    #pragma unroll
    for (int off = 1; off < 64; off <<= 1) acc += __shfl_xor(acc, off);
    if (lane == 0) ws[wv] = acc;
    __syncthreads();
    if (tid == 0) boff_s = ws[0] + ws[1] + ws[2] + ws[3];
    __syncthreads();
    int i = c * 256 + tid;
    int v = (i < N) ? count[i] : 0;
    int incl = v;
    #pragma unroll
    for (int off = 1; off < 64; off <<= 1) {
        int t = __shfl_up(incl, off);
        if (lane >= off) incl += t;
    }
    if (lane == 63) ws[wv] = incl;
    __syncthreads();
    int wofs = 0;
    #pragma unroll
    for (int w = 0; w < 4; ++w) if (w < wv) wofs += ws[w];
    int excl = boff_s + wofs + incl - v;
    if (i < N) { row_start[i] = excl; cursor[i] = excl; }
    else if (i == N) row_start[N] = excl;
}

// ---------- D4: scatter + edge-score precompute ----------
__global__ __launch_bounds__(256) void scatter_score_kernel(
        const int* __restrict__ src, const int* __restrict__ dst,
        const float* __restrict__ el, const float* __restrict__ er,
        int* __restrict__ cursor, int4* __restrict__ pay, int E) {
    int i = blockIdx.x * 256 + threadIdx.x;
    if (i >= E) return;
    int s = src[i], d = dst[i];
    float4 l = ((const float4*)el)[s];
    float4 r = ((const float4*)er)[d];
    float v0 = l.x + r.x, v1 = l.y + r.y, v2 = l.z + r.z, v3 = l.w + r.w;
    v0 = v0 > 0.f ? v0 : NEG_SLOPE * v0;
    v1 = v1 > 0.f ? v1 : NEG_SLOPE * v1;
    v2 = v2 > 0.f ? v2 : NEG_SLOPE * v2;
    v3 = v3 > 0.f ? v3 : NEG_SLOPE * v3;
    int e01 = (int)f2h(__expf(v0)) | ((int)f2h(__expf(v1)) << 16);
    int e23 = (int)f2h(__expf(v2)) | ((int)f2h(__expf(v3)) << 16);
    int pos = atomicAdd(&cursor[d], 1);
    pay[pos] = make_int4(s, e01, e23, 0);
}

// ---------- D5: fused normalize + aggregate (R7-proven: 4-way, 28 VGPR) ----
#define AGG_ONE(Q) do {                                             \
    float e_ = esel((Q), h);                                        \
    dh += e_;                                                       \
    ushort4 fv_ = *(const ushort4*)(featb + ((size_t)(Q).x << 8) + col); \
    ax += e_ * bf2f(fv_.x); ay += e_ * bf2f(fv_.y);                 \
    az += e_ * bf2f(fv_.z); aw += e_ * bf2f(fv_.w); } while (0)

__global__ __launch_bounds__(256) void node_aggregate_kernel(
        const unsigned short* __restrict__ featb, const int4* __restrict__ pay,
        const int* __restrict__ row_start, float* __restrict__ out, int N) {
    int wid = blockIdx.x * 4 + (threadIdx.x >> 6);
    int lane = threadIdx.x & 63;
    if (wid >= N) return;
    const int beg = row_start[wid], end = row_start[wid + 1];
    if (beg == end) {
        if (lane < 16) *(float4*)(out + (size_t)wid * HID + lane * 4) = make_float4(0.f, 0.f, 0.f, 0.f);
        return;
    }
    const int h = lane >> 4;
    const int col = lane * 4;

    float dh = 0.f, ax = 0.f, ay = 0.f, az = 0.f, aw = 0.f;
    int p = beg;
    for (; p + 4 <= end; p += 4) {
        int4 q0 = pay[p], q1 = pay[p + 1], q2 = pay[p + 2], q3 = pay[p + 3];
        float e0 = esel(q0, h), e1 = esel(q1, h), e2 = esel(q2, h), e3 = esel(q3, h);
        ushort4 f0 = *(const ushort4*)(featb + ((size_t)q0.x << 8) + col);
        ushort4 f1 = *(const ushort4*)(featb + ((size_t)q1.x << 8) + col);
        ushort4 f2 = *(const ushort4*)(featb + ((size_t)q2.x << 8) + col);
        ushort4 f3 = *(const ushort4*)(featb + ((size_t)q3.x << 8) + col);
        dh += (e0 + e1) + (e2 + e3);
        ax += e0 * bf2f(f0.x) + e1 * bf2f(f1.x) + e2 * bf2f(f2.x) + e3 * bf2f(f3.x);
        ay += e0 * bf2f(f0.y) + e1 * bf2f(f1.y) + e2 * bf2f(f2.y) + e3 * bf2f(f3.y);
        az += e0 * bf2f(f0.z) + e1 * bf2f(f1.z) + e2 * bf2f(f2.z) + e3 * bf2f(f3.z);
        aw += e0 * bf2f(f0.w) + e1 * bf2f(f1.w) + e2 * bf2f(f2.w) + e3 * bf2f(f3.w);
    }
    for (; p < end; ++p) { int4 q = pay[p]; AGG_ONE(q); }

    float inv = 1.f / dh;
    float rx = ax * inv, ry = ay * inv, rz = az * inv, rw = aw * inv;
    rx += __shfl_xor(rx, 16); ry += __shfl_xor(ry, 16);
    rz += __shfl_xor(rz, 16); rw += __shfl_xor(rw, 16);
    rx += __shfl_xor(rx, 32); ry += __shfl_xor(ry, 32);
    rz += __shfl_xor(rz, 32); rw += __shfl_xor(rw, 32);
    if (lane < 16) {
        *(float4*)(out + (size_t)wid * HID + lane * 4) =
            make_float4(0.25f * rx, 0.25f * ry, 0.25f * rz, 0.25f * rw);
    }
}

extern "C" void kernel_launch(void* const* d_in, const int* in_sizes, int n_in,
                              void* d_out, int out_size, void* d_ws, size_t ws_size,
                              hipStream_t stream) {
    const float* x      = (const float*)d_in[0];
    const float* W      = (const float*)d_in[1];
    const float* attn_l = (const float*)d_in[2];
    const float* attn_r = (const float*)d_in[3];
    const int*   src    = (const int*)d_in[4];
    const int*   dst    = (const int*)d_in[5];
    float* out = (float*)d_out;

    const int N = in_sizes[0] / IN_DIM;   // 50000
    const int E = in_sizes[4];            // 800000

    // workspace layout (16B-aligned sections)
    int4*  pay       = (int4*)d_ws;                             // E x 16B
    unsigned short* wtp   = (unsigned short*)d_ws + (size_t)N * IN_DIM; // 256*256 bf16
    unsigned short* featb = wtp + 256 * 256;                    // N*256 bf16
    float* el        = (float*)(featb + (size_t)N * IN_DIM);    // N*4
    float* er        = el + (size_t)N * HEADS;                  // N*4
    int*   count     = (int*)(er + (size_t)N * HEADS);          // N
    int*   row_start = count + N;                               // N+1 (+pad)
    int*   cursor    = row_start + N + 4;                       // N

    const int NB = (N + 1 + 255) / 256;
    const int GB = (N + BM - 1) / BM;     // 391 GEMM blocks
    const int HB = 128;                   // hist blocks (512 thr each)

    // D1: zero count + cast/transpose W
    prep0_kernel<<<256, 256, 0, stream>>>(W, wtp, count, N);

    // D2: GEMM(+el/er) ∪ dst histogram
    gemm_hist_kernel<<<GB + HB, 512, 0, stream>>>(
        x, wtp, attn_l, attn_r, featb, el, er, N, GB, dst, count, E);

    // D3: scan -> row_start, cursor
    scan_kernel<<<NB, 256, 0, stream>>>(count, row_start, cursor, N);

    // D4: scatter + edge-score precompute
    scatter_score_kernel<<<(E + 255) / 256, 256, 0, stream>>>(
        src, dst, el, er, cursor, pay, E);

    // D5: fused normalize + aggregate
    node_aggregate_kernel<<<(N * 64 + 255) / 256, 256, 0, stream>>>(
        featb, pay, row_start, out, N);
}